// Round 6
// baseline (318.168 us; speedup 1.0000x reference)
//
#include <hip/hip_runtime.h>
#include <hip/hip_bf16.h>
#include <math.h>

#define N_EMBD 1024
#define N_HEAD 16
#define HS 64
#define BT 4096
#define TSEQ 2048

typedef float f32x4 __attribute__((ext_vector_type(4)));
typedef short bf16x8 __attribute__((ext_vector_type(8)));
typedef unsigned short u16;

static __device__ __forceinline__ u16 f2bf(float f) {
  union { float f; unsigned int u; } c; c.f = f;
  unsigned int r = c.u + 0x7FFFu + ((c.u >> 16) & 1u);   // RNE
  return (u16)(r >> 16);
}

static __device__ __forceinline__ u16 f2bf_fast(float f) {
  union { __hip_bfloat16 h; u16 u; } cv;
  cv.h = __float2bfloat16(f);
  return cv.u;
}

// ---------------- prep: fp32 -> bf16 elementwise (x)
__global__ __launch_bounds__(256) void cvt_bf16(const float* __restrict__ in,
                                                u16* __restrict__ out, int n4) {
  int i = blockIdx.x * 256 + threadIdx.x;
  if (i < n4) {
    float4 v = ((const float4*)in)[i];
    ushort4 o;
    o.x = f2bf(v.x); o.y = f2bf(v.y); o.z = f2bf(v.z); o.w = f2bf(v.w);
    ((ushort4*)out)[i] = o;
  }
}

// ---------------- prep: W[K][N] fp32 -> Wt[N][K] bf16 (32x32 LDS transpose)
__global__ __launch_bounds__(256) void transpose_cvt(const float* __restrict__ W,
                                                     u16* __restrict__ Wt,
                                                     int K, int N) {
  __shared__ u16 Ls[32][36];
  const int n0 = blockIdx.x * 32, k0 = blockIdx.y * 32;
  const int t = threadIdx.x;
  {
    int kk = t >> 3, nn4 = (t & 7) * 4;
    float4 v = *(const float4*)(W + (size_t)(k0 + kk) * N + n0 + nn4);
    Ls[kk][nn4 + 0] = f2bf(v.x); Ls[kk][nn4 + 1] = f2bf(v.y);
    Ls[kk][nn4 + 2] = f2bf(v.z); Ls[kk][nn4 + 3] = f2bf(v.w);
  }
  __syncthreads();
  {
    int nn = t >> 3, kk4 = (t & 7) * 4;
    ushort4 o;
    o.x = Ls[kk4 + 0][nn]; o.y = Ls[kk4 + 1][nn];
    o.z = Ls[kk4 + 2][nn]; o.w = Ls[kk4 + 3][nn];
    *(ushort4*)(Wt + (size_t)(n0 + nn) * K + k0 + kk4) = o;
  }
}

// ---------------- bf16 MFMA GEMM core (m97 structure)
#define BKS 32

__device__ __forceinline__ int swz(int row, int c) {
  return row * 4 + (c ^ ((row >> 1) & 3));
}

__device__ __forceinline__ void stage128x32(const u16* __restrict__ G, int ldk,
                                            u16* lds, int w, int lane) {
#pragma unroll
  for (int i = 0; i < 2; ++i) {
    int s = i * 256 + w * 64 + lane;
    int row = s >> 2, c = s & 3;
    int csrc = c ^ ((row >> 1) & 3);
    const u16* src = G + (size_t)row * ldk + csrc * 8;
    u16* dst = lds + (size_t)(i * 256 + w * 64) * 8;
    __builtin_amdgcn_global_load_lds(
        (const __attribute__((address_space(1))) void*)src,
        (__attribute__((address_space(3))) void*)dst, 16, 0, 0);
  }
}

#define GEMM_MAIN_LOOP(Aptr, Bptr, Kdim)                                        \
  __shared__ u16 sm[2][2][128 * BKS];                                           \
  const int tid = threadIdx.x, lane = tid & 63, w = tid >> 6;                   \
  const int wr = w >> 1, wc = w & 1, lrow = lane & 15, lhi = lane >> 4;         \
  const int bm = blockIdx.y * 128, bn = blockIdx.x * 128;                       \
  f32x4 acc[4][4];                                                              \
  _Pragma("unroll") for (int i = 0; i < 4; ++i)                                 \
      _Pragma("unroll") for (int j = 0; j < 4; ++j)                             \
          acc[i][j] = (f32x4){0.f, 0.f, 0.f, 0.f};                              \
  stage128x32(Aptr + (size_t)bm * Kdim, Kdim, sm[0][0], w, lane);               \
  stage128x32(Bptr + (size_t)bn * Kdim, Kdim, sm[0][1], w, lane);               \
  __syncthreads();                                                              \
  const int NT = Kdim / BKS;                                                    \
  for (int t = 0; t < NT; ++t) {                                                \
    int cur = t & 1, nxt = cur ^ 1;                                             \
    if (t + 1 < NT) {                                                           \
      stage128x32(Aptr + (size_t)bm * Kdim + (t + 1) * BKS, Kdim, sm[nxt][0],   \
                  w, lane);                                                     \
      stage128x32(Bptr + (size_t)bn * Kdim + (t + 1) * BKS, Kdim, sm[nxt][1],   \
                  w, lane);                                                     \
    }                                                                           \
    const u16* As = sm[cur][0];                                                 \
    const u16* Bs = sm[cur][1];                                                 \
    bf16x8 af[4], bfr[4];                                                       \
    _Pragma("unroll") for (int mi = 0; mi < 4; ++mi) {                          \
      int row = wr * 64 + mi * 16 + lrow;                                       \
      af[mi] = *(const bf16x8*)(As + (size_t)swz(row, lhi) * 8);                \
    }                                                                           \
    _Pragma("unroll") for (int nj = 0; nj < 4; ++nj) {                          \
      int row = wc * 64 + nj * 16 + lrow;                                       \
      bfr[nj] = *(const bf16x8*)(Bs + (size_t)swz(row, lhi) * 8);               \
    }                                                                           \
    _Pragma("unroll") for (int mi = 0; mi < 4; ++mi)                            \
        _Pragma("unroll") for (int nj = 0; nj < 4; ++nj)                        \
            acc[mi][nj] = __builtin_amdgcn_mfma_f32_16x16x32_bf16(              \
                af[mi], bfr[nj], acc[mi][nj], 0, 0, 0);                         \
    __syncthreads();                                                            \
  }

// QKV GEMM epilogue -> Qb (scaled by 0.125*log2e), Kb, Vt
__global__ __launch_bounds__(256) void gemm_qkv_bf16(
    const u16* __restrict__ Ab, const u16* __restrict__ Btr,
    const float* __restrict__ bias,
    u16* __restrict__ Qb, u16* __restrict__ Kb, u16* __restrict__ Vt) {
  GEMM_MAIN_LOOP(Ab, Btr, N_EMBD)
  const int sector = bn >> 10;
  const float QSC = 0.125f * 1.44269504f;   // fold log2(e) for exp2 softmax
#pragma unroll
  for (int nj = 0; nj < 4; ++nj) {
    int n = bn + wc * 64 + nj * 16 + lrow;
    int h = (n & 1023) >> 6, d = n & 63;
    float bv = bias[n];
#pragma unroll
    for (int mi = 0; mi < 4; ++mi) {
      int mbase = bm + wr * 64 + mi * 16 + lhi * 4;
      int bb_ = mbase >> 11, tt = mbase & 2047;
      if (sector == 0) {
#pragma unroll
        for (int r = 0; r < 4; ++r)
          Qb[((size_t)(bb_ * 16 + h) * TSEQ + tt + r) * HS + d] =
              f2bf((acc[mi][nj][r] + bv) * QSC);
      } else if (sector == 1) {
#pragma unroll
        for (int r = 0; r < 4; ++r)
          Kb[((size_t)(bb_ * 16 + h) * TSEQ + tt + r) * HS + d] =
              f2bf(acc[mi][nj][r] + bv);
      } else {
        ushort4 o;
        o.x = f2bf(acc[mi][nj][0] + bv); o.y = f2bf(acc[mi][nj][1] + bv);
        o.z = f2bf(acc[mi][nj][2] + bv); o.w = f2bf(acc[mi][nj][3] + bv);
        *(ushort4*)(Vt + ((size_t)(bb_ * 16 + h) * HS + d) * TSEQ + tt) = o;
      }
    }
  }
}

// Proj GEMM epilogue -> fp32 out + bias
__global__ __launch_bounds__(256) void gemm_proj_bf16(
    const u16* __restrict__ Ab, const u16* __restrict__ Btr,
    const float* __restrict__ bias, float* __restrict__ C) {
  GEMM_MAIN_LOOP(Ab, Btr, N_EMBD)
#pragma unroll
  for (int nj = 0; nj < 4; ++nj) {
    int n = bn + wc * 64 + nj * 16 + lrow;
    float bv = bias[n];
#pragma unroll
    for (int mi = 0; mi < 4; ++mi) {
      int mbase = bm + wr * 64 + mi * 16 + lhi * 4;
#pragma unroll
      for (int r = 0; r < 4; ++r)
        C[(size_t)(mbase + r) * N_EMBD + n] = acc[mi][nj][r] + bv;
    }
  }
}

// ---------------- MFMA flash attention v3
// 2 waves per block; wave handles ONE 16-row q-tile: wave0 -> pr, wave1 -> 127-pr
// (uniform triangle pairing). 4096 waves total. XCD-aware bh decode.
// K double-buffered in regs; V issued at step top; defer-rescale (THR=8, log2).
struct Kfrag { bf16x8 r[8]; };

__device__ __forceinline__ void loadK(const u16* __restrict__ Kh, int kb,
                                      int lrow, int lhi, Kfrag& kf) {
#pragma unroll
  for (int s = 0; s < 4; ++s) {
    const u16* base = Kh + (size_t)(kb + 16 * s + lrow) * HS + lhi * 8;
    kf.r[2 * s]     = *(const bf16x8*)(base);
    kf.r[2 * s + 1] = *(const bf16x8*)(base + 32);
  }
}

__global__ __launch_bounds__(128, 4) void attn_mfma(
    const u16* __restrict__ Qb, const u16* __restrict__ Kb,
    const u16* __restrict__ Vt, u16* __restrict__ Y) {
  __shared__ u16 Plds[2][16][72];

  const int tid  = threadIdx.x;
  const int lane = tid & 63;
  const int w    = tid >> 6;
  const int lrow = lane & 15;
  const int lhi  = lane >> 4;

  const int wg  = blockIdx.x;
  const int lin = wg >> 3;                   // 0..255
  const int bh  = ((wg & 7) << 2) | (lin >> 6);
  const int pr  = lin & 63;                  // pair index 0..63
  const int b   = bh >> 4, h = bh & 15;

  const u16* Qh = Qb + (size_t)bh * TSEQ * HS;
  const u16* Kh = Kb + (size_t)bh * TSEQ * HS;
  const u16* Vh = Vt + (size_t)bh * HS * TSEQ;

  u16 (*PW)[72] = Plds[w];

  const int itile = w ? (127 - pr) : pr;
  const int q0w  = itile * 16;
  const int kend = (q0w / 64 + 1) * 64;      // keys rounded up to 64

  bf16x8 aq0 = *(const bf16x8*)(Qh + (size_t)(q0w + lrow) * HS + lhi * 8);
  bf16x8 aq1 = *(const bf16x8*)(Qh + (size_t)(q0w + lrow) * HS + 32 + lhi * 8);

  f32x4 o[4];
  float m_[4], l_[4];
#pragma unroll
  for (int r = 0; r < 4; ++r) { m_[r] = -INFINITY; l_[r] = 0.f; }
#pragma unroll
  for (int ds = 0; ds < 4; ++ds) o[ds] = (f32x4){0.f, 0.f, 0.f, 0.f};

  Kfrag kA, kB;
  loadK(Kh, 0, lrow, lhi, kA);
  int kb = 0;

#define ATTN_STEP(KC, KN)                                                      \
  {                                                                            \
    bf16x8 vf[8];                                                              \
    _Pragma("unroll") for (int ks = 0; ks < 2; ++ks)                           \
      _Pragma("unroll") for (int ds = 0; ds < 4; ++ds)                         \
        vf[ks * 4 + ds] = *(const bf16x8*)(                                    \
            Vh + (size_t)(ds * 16 + lrow) * TSEQ + kb + ks * 32 + lhi * 8);    \
    if (kb + 64 < kend) loadK(Kh, kb + 64, lrow, lhi, KN);                     \
    f32x4 sacc[4];                                                             \
    _Pragma("unroll") for (int s = 0; s < 4; ++s) {                            \
      f32x4 z = (f32x4){0.f, 0.f, 0.f, 0.f};                                   \
      z = __builtin_amdgcn_mfma_f32_16x16x32_bf16(aq0, KC.r[2 * s], z, 0, 0, 0); \
      z = __builtin_amdgcn_mfma_f32_16x16x32_bf16(aq1, KC.r[2 * s + 1], z, 0, 0, 0); \
      sacc[s] = z;                                                             \
    }                                                                          \
    const bool last = (kb + 64 >= kend);                                       \
    if (last) {                                                                \
      _Pragma("unroll") for (int s = 0; s < 4; ++s) {                          \
        int kg = kb + 16 * s + lrow;                                           \
        _Pragma("unroll") for (int r = 0; r < 4; ++r) {                        \
          int qg = q0w + lhi * 4 + r;                                          \
          if (kg > qg) sacc[s][r] = -3.0e38f;                                  \
        }                                                                      \
      }                                                                        \
    }                                                                          \
    float corr[4];                                                             \
    bool nr[4];                                                                \
    _Pragma("unroll") for (int r = 0; r < 4; ++r) {                            \
      float mx = fmaxf(fmaxf(sacc[0][r], sacc[1][r]),                          \
                       fmaxf(sacc[2][r], sacc[3][r]));                         \
      _Pragma("unroll") for (int off = 1; off <= 8; off <<= 1)                 \
          mx = fmaxf(mx, __shfl_xor(mx, off));                                 \
      nr[r] = !__all(mx <= m_[r] + 8.0f);                                      \
      if (nr[r]) {                                                             \
        float mnew = fmaxf(m_[r], mx);                                         \
        corr[r] = exp2f(m_[r] - mnew);                                         \
        m_[r] = mnew;                                                          \
        l_[r] *= corr[r];                                                      \
      }                                                                        \
      float ps = 0.f;                                                          \
      _Pragma("unroll") for (int s = 0; s < 4; ++s) {                          \
        float p = exp2f(sacc[s][r] - m_[r]);                                   \
        ps += p;                                                               \
        PW[lhi * 4 + r][s * 16 + lrow] = f2bf_fast(p);                         \
      }                                                                        \
      _Pragma("unroll") for (int off = 1; off <= 8; off <<= 1)                 \
          ps += __shfl_xor(ps, off);                                           \
      l_[r] += ps;                                                             \
    }                                                                          \
    _Pragma("unroll") for (int r = 0; r < 4; ++r)                              \
      if (nr[r]) {                                                             \
        _Pragma("unroll") for (int ds = 0; ds < 4; ++ds) o[ds][r] *= corr[r];  \
      }                                                                        \
    _Pragma("unroll") for (int ks = 0; ks < 2; ++ks) {                         \
      bf16x8 pa = *(const bf16x8*)&PW[lrow][ks * 32 + lhi * 8];                \
      _Pragma("unroll") for (int ds = 0; ds < 4; ++ds)                         \
        o[ds] = __builtin_amdgcn_mfma_f32_16x16x32_bf16(                       \
            pa, vf[ks * 4 + ds], o[ds], 0, 0, 0);                              \
    }                                                                          \
    kb += 64;                                                                  \
  }

  while (true) {
    ATTN_STEP(kA, kB)
    if (kb >= kend) break;
    ATTN_STEP(kB, kA)
    if (kb >= kend) break;
  }
#undef ATTN_STEP

  // epilogue
#pragma unroll
  for (int r = 0; r < 4; ++r) {
    float inv = 1.0f / l_[r];
    int q = q0w + lhi * 4 + r;
#pragma unroll
    for (int ds = 0; ds < 4; ++ds)
      Y[((size_t)(b * TSEQ + q)) * N_EMBD + h * HS + ds * 16 + lrow] =
          f2bf(o[ds][r] * inv);
  }
}

extern "C" void kernel_launch(void* const* d_in, const int* in_sizes, int n_in,
                              void* d_out, int out_size, void* d_ws, size_t ws_size,
                              hipStream_t stream) {
  const float* x      = (const float*)d_in[0];
  const float* W_attn = (const float*)d_in[1];
  const float* b_attn = (const float*)d_in[2];
  const float* W_proj = (const float*)d_in[3];
  const float* b_proj = (const float*)d_in[4];
  float* out = (float*)d_out;

  u16* xb  = (u16*)d_ws;
  u16* Wat = xb  + (size_t)BT * N_EMBD;
  u16* Wpt = Wat + (size_t)3 * N_EMBD * N_EMBD;
  u16* Qb  = Wpt + (size_t)N_EMBD * N_EMBD;
  u16* Kb  = Qb  + (size_t)BT * N_EMBD;
  u16* Vt  = Kb  + (size_t)BT * N_EMBD;
  u16* yb  = Vt  + (size_t)BT * N_EMBD;

  cvt_bf16<<<(BT * N_EMBD / 4 + 255) / 256, 256, 0, stream>>>(x, xb, BT * N_EMBD / 4);
  {
    dim3 g1(3 * N_EMBD / 32, N_EMBD / 32);
    transpose_cvt<<<g1, 256, 0, stream>>>(W_attn, Wat, N_EMBD, 3 * N_EMBD);
    dim3 g2(N_EMBD / 32, N_EMBD / 32);
    transpose_cvt<<<g2, 256, 0, stream>>>(W_proj, Wpt, N_EMBD, N_EMBD);
  }
  {
    dim3 grid(3 * N_EMBD / 128, BT / 128);
    gemm_qkv_bf16<<<grid, 256, 0, stream>>>(xb, Wat, b_attn, Qb, Kb, Vt);
  }
  {
    attn_mfma<<<2048, 128, 0, stream>>>(Qb, Kb, Vt, yb);
  }
  {
    dim3 grid(N_EMBD / 128, BT / 128);
    gemm_proj_bf16<<<grid, 256, 0, stream>>>(yb, Wpt, b_proj, out);
  }
}

// Round 7
// 276.074 us; speedup vs baseline: 1.1525x; 1.1525x over previous
//
#include <hip/hip_runtime.h>
#include <hip/hip_bf16.h>
#include <math.h>

#define N_EMBD 1024
#define N_HEAD 16
#define HS 64
#define BT 4096
#define TSEQ 2048

typedef float f32x4 __attribute__((ext_vector_type(4)));
typedef short bf16x8 __attribute__((ext_vector_type(8)));
typedef unsigned short u16;

static __device__ __forceinline__ u16 f2bf(float f) {
  union { float f; unsigned int u; } c; c.f = f;
  unsigned int r = c.u + 0x7FFFu + ((c.u >> 16) & 1u);   // RNE
  return (u16)(r >> 16);
}

static __device__ __forceinline__ u16 f2bf_fast(float f) {
  union { __hip_bfloat16 h; u16 u; } cv;
  cv.h = __float2bfloat16(f);
  return cv.u;
}

// ---------------- prep: fp32 -> bf16 elementwise (x)
__global__ __launch_bounds__(256) void cvt_bf16(const float* __restrict__ in,
                                                u16* __restrict__ out, int n4) {
  int i = blockIdx.x * 256 + threadIdx.x;
  if (i < n4) {
    float4 v = ((const float4*)in)[i];
    ushort4 o;
    o.x = f2bf(v.x); o.y = f2bf(v.y); o.z = f2bf(v.z); o.w = f2bf(v.w);
    ((ushort4*)out)[i] = o;
  }
}

// ---------------- prep: W[K][N] fp32 -> Wt[N][K] bf16 (32x32 LDS transpose)
__global__ __launch_bounds__(256) void transpose_cvt(const float* __restrict__ W,
                                                     u16* __restrict__ Wt,
                                                     int K, int N) {
  __shared__ u16 Ls[32][36];
  const int n0 = blockIdx.x * 32, k0 = blockIdx.y * 32;
  const int t = threadIdx.x;
  {
    int kk = t >> 3, nn4 = (t & 7) * 4;
    float4 v = *(const float4*)(W + (size_t)(k0 + kk) * N + n0 + nn4);
    Ls[kk][nn4 + 0] = f2bf(v.x); Ls[kk][nn4 + 1] = f2bf(v.y);
    Ls[kk][nn4 + 2] = f2bf(v.z); Ls[kk][nn4 + 3] = f2bf(v.w);
  }
  __syncthreads();
  {
    int nn = t >> 3, kk4 = (t & 7) * 4;
    ushort4 o;
    o.x = Ls[kk4 + 0][nn]; o.y = Ls[kk4 + 1][nn];
    o.z = Ls[kk4 + 2][nn]; o.w = Ls[kk4 + 3][nn];
    *(ushort4*)(Wt + (size_t)(n0 + nn) * K + k0 + kk4) = o;
  }
}

// ---------------- bf16 MFMA GEMM core (m97 structure)
#define BKS 32

__device__ __forceinline__ int swz(int row, int c) {
  return row * 4 + (c ^ ((row >> 1) & 3));
}

__device__ __forceinline__ void stage128x32(const u16* __restrict__ G, int ldk,
                                            u16* lds, int w, int lane) {
#pragma unroll
  for (int i = 0; i < 2; ++i) {
    int s = i * 256 + w * 64 + lane;
    int row = s >> 2, c = s & 3;
    int csrc = c ^ ((row >> 1) & 3);
    const u16* src = G + (size_t)row * ldk + csrc * 8;
    u16* dst = lds + (size_t)(i * 256 + w * 64) * 8;
    __builtin_amdgcn_global_load_lds(
        (const __attribute__((address_space(1))) void*)src,
        (__attribute__((address_space(3))) void*)dst, 16, 0, 0);
  }
}

#define GEMM_MAIN_LOOP(Aptr, Bptr, Kdim)                                        \
  __shared__ u16 sm[2][2][128 * BKS];                                           \
  const int tid = threadIdx.x, lane = tid & 63, w = tid >> 6;                   \
  const int wr = w >> 1, wc = w & 1, lrow = lane & 15, lhi = lane >> 4;         \
  const int bm = blockIdx.y * 128, bn = blockIdx.x * 128;                       \
  f32x4 acc[4][4];                                                              \
  _Pragma("unroll") for (int i = 0; i < 4; ++i)                                 \
      _Pragma("unroll") for (int j = 0; j < 4; ++j)                             \
          acc[i][j] = (f32x4){0.f, 0.f, 0.f, 0.f};                              \
  stage128x32(Aptr + (size_t)bm * Kdim, Kdim, sm[0][0], w, lane);               \
  stage128x32(Bptr + (size_t)bn * Kdim, Kdim, sm[0][1], w, lane);               \
  __syncthreads();                                                              \
  const int NT = Kdim / BKS;                                                    \
  for (int t = 0; t < NT; ++t) {                                                \
    int cur = t & 1, nxt = cur ^ 1;                                             \
    if (t + 1 < NT) {                                                           \
      stage128x32(Aptr + (size_t)bm * Kdim + (t + 1) * BKS, Kdim, sm[nxt][0],   \
                  w, lane);                                                     \
      stage128x32(Bptr + (size_t)bn * Kdim + (t + 1) * BKS, Kdim, sm[nxt][1],   \
                  w, lane);                                                     \
    }                                                                           \
    const u16* As = sm[cur][0];                                                 \
    const u16* Bs = sm[cur][1];                                                 \
    bf16x8 af[4], bfr[4];                                                       \
    _Pragma("unroll") for (int mi = 0; mi < 4; ++mi) {                          \
      int row = wr * 64 + mi * 16 + lrow;                                       \
      af[mi] = *(const bf16x8*)(As + (size_t)swz(row, lhi) * 8);                \
    }                                                                           \
    _Pragma("unroll") for (int nj = 0; nj < 4; ++nj) {                          \
      int row = wc * 64 + nj * 16 + lrow;                                       \
      bfr[nj] = *(const bf16x8*)(Bs + (size_t)swz(row, lhi) * 8);               \
    }                                                                           \
    _Pragma("unroll") for (int mi = 0; mi < 4; ++mi)                            \
        _Pragma("unroll") for (int nj = 0; nj < 4; ++nj)                        \
            acc[mi][nj] = __builtin_amdgcn_mfma_f32_16x16x32_bf16(              \
                af[mi], bfr[nj], acc[mi][nj], 0, 0, 0);                         \
    __syncthreads();                                                            \
  }

// QKV GEMM epilogue -> Qb (scaled by 0.125*log2e), Kb, Vt
__global__ __launch_bounds__(256) void gemm_qkv_bf16(
    const u16* __restrict__ Ab, const u16* __restrict__ Btr,
    const float* __restrict__ bias,
    u16* __restrict__ Qb, u16* __restrict__ Kb, u16* __restrict__ Vt) {
  GEMM_MAIN_LOOP(Ab, Btr, N_EMBD)
  const int sector = bn >> 10;
  const float QSC = 0.125f * 1.44269504f;   // fold log2(e) for exp2 softmax
#pragma unroll
  for (int nj = 0; nj < 4; ++nj) {
    int n = bn + wc * 64 + nj * 16 + lrow;
    int h = (n & 1023) >> 6, d = n & 63;
    float bv = bias[n];
#pragma unroll
    for (int mi = 0; mi < 4; ++mi) {
      int mbase = bm + wr * 64 + mi * 16 + lhi * 4;
      int bb_ = mbase >> 11, tt = mbase & 2047;
      if (sector == 0) {
#pragma unroll
        for (int r = 0; r < 4; ++r)
          Qb[((size_t)(bb_ * 16 + h) * TSEQ + tt + r) * HS + d] =
              f2bf((acc[mi][nj][r] + bv) * QSC);
      } else if (sector == 1) {
#pragma unroll
        for (int r = 0; r < 4; ++r)
          Kb[((size_t)(bb_ * 16 + h) * TSEQ + tt + r) * HS + d] =
              f2bf(acc[mi][nj][r] + bv);
      } else {
        ushort4 o;
        o.x = f2bf(acc[mi][nj][0] + bv); o.y = f2bf(acc[mi][nj][1] + bv);
        o.z = f2bf(acc[mi][nj][2] + bv); o.w = f2bf(acc[mi][nj][3] + bv);
        *(ushort4*)(Vt + ((size_t)(bb_ * 16 + h) * HS + d) * TSEQ + tt) = o;
      }
    }
  }
}

// Proj GEMM epilogue -> fp32 out + bias
__global__ __launch_bounds__(256) void gemm_proj_bf16(
    const u16* __restrict__ Ab, const u16* __restrict__ Btr,
    const float* __restrict__ bias, float* __restrict__ C) {
  GEMM_MAIN_LOOP(Ab, Btr, N_EMBD)
#pragma unroll
  for (int nj = 0; nj < 4; ++nj) {
    int n = bn + wc * 64 + nj * 16 + lrow;
    float bv = bias[n];
#pragma unroll
    for (int mi = 0; mi < 4; ++mi) {
      int mbase = bm + wr * 64 + mi * 16 + lhi * 4;
#pragma unroll
      for (int r = 0; r < 4; ++r)
        C[(size_t)(mbase + r) * N_EMBD + n] = acc[mi][nj][r] + bv;
    }
  }
}

// ---------------- MFMA flash attention v4
// 4 waves/block, each wave ONE 16-row q-tile: block j -> tiles {4j,4j+1,4j+2,4j+3},
// all exactly j+1 k-steps (uniform). Long blocks dispatch first. 1024 blocks.
// XCD-aware bh decode (4 bh per XCD -> 2MB L2 set). K reg-dbuf; V issue-early;
// defer-rescale THR=8 (log2 domain). NO tight VGPR clamp (R6 spill lesson).
struct Kfrag { bf16x8 r[8]; };

__device__ __forceinline__ void loadK(const u16* __restrict__ Kh, int kb,
                                      int lrow, int lhi, Kfrag& kf) {
#pragma unroll
  for (int s = 0; s < 4; ++s) {
    const u16* base = Kh + (size_t)(kb + 16 * s + lrow) * HS + lhi * 8;
    kf.r[2 * s]     = *(const bf16x8*)(base);
    kf.r[2 * s + 1] = *(const bf16x8*)(base + 32);
  }
}

__global__ __launch_bounds__(256, 3) void attn_mfma(
    const u16* __restrict__ Qb, const u16* __restrict__ Kb,
    const u16* __restrict__ Vt, u16* __restrict__ Y) {
  __shared__ u16 Plds[4][16][72];

  const int tid  = threadIdx.x;
  const int lane = tid & 63;
  const int w    = tid >> 6;
  const int lrow = lane & 15;
  const int lhi  = lane >> 4;

  const int wg  = blockIdx.x;                  // 0..1023
  const int xcd = wg & 7;
  const int lin = wg >> 3;                     // 0..127
  const int bh  = (xcd << 2) | (lin >> 5);     // 4 bh per XCD
  const int j   = 31 - (lin & 31);             // long blocks first
  const int b   = bh >> 4, h = bh & 15;

  const u16* Qh = Qb + (size_t)bh * TSEQ * HS;
  const u16* Kh = Kb + (size_t)bh * TSEQ * HS;
  const u16* Vh = Vt + (size_t)bh * HS * TSEQ;

  u16 (*PW)[72] = Plds[w];

  const int itile = 4 * j + w;                 // this wave's q-tile
  const int q0w  = itile * 16;
  const int kend = (j + 1) * 64;               // uniform across the block

  bf16x8 aq0 = *(const bf16x8*)(Qh + (size_t)(q0w + lrow) * HS + lhi * 8);
  bf16x8 aq1 = *(const bf16x8*)(Qh + (size_t)(q0w + lrow) * HS + 32 + lhi * 8);

  f32x4 o[4];
  float m_[4], l_[4];
#pragma unroll
  for (int r = 0; r < 4; ++r) { m_[r] = -INFINITY; l_[r] = 0.f; }
#pragma unroll
  for (int ds = 0; ds < 4; ++ds) o[ds] = (f32x4){0.f, 0.f, 0.f, 0.f};

  Kfrag kA, kB;
  loadK(Kh, 0, lrow, lhi, kA);
  int kb = 0;

#define ATTN_STEP(KC, KN)                                                      \
  {                                                                            \
    bf16x8 vf[8];                                                              \
    _Pragma("unroll") for (int ks = 0; ks < 2; ++ks)                           \
      _Pragma("unroll") for (int ds = 0; ds < 4; ++ds)                         \
        vf[ks * 4 + ds] = *(const bf16x8*)(                                    \
            Vh + (size_t)(ds * 16 + lrow) * TSEQ + kb + ks * 32 + lhi * 8);    \
    if (kb + 64 < kend) loadK(Kh, kb + 64, lrow, lhi, KN);                     \
    f32x4 sacc[4];                                                             \
    _Pragma("unroll") for (int s = 0; s < 4; ++s) {                            \
      f32x4 z = (f32x4){0.f, 0.f, 0.f, 0.f};                                   \
      z = __builtin_amdgcn_mfma_f32_16x16x32_bf16(aq0, KC.r[2 * s], z, 0, 0, 0); \
      z = __builtin_amdgcn_mfma_f32_16x16x32_bf16(aq1, KC.r[2 * s + 1], z, 0, 0, 0); \
      sacc[s] = z;                                                             \
    }                                                                          \
    const bool last = (kb + 64 >= kend);                                       \
    if (last) {                                                                \
      _Pragma("unroll") for (int s = 0; s < 4; ++s) {                          \
        int kg = kb + 16 * s + lrow;                                           \
        _Pragma("unroll") for (int r = 0; r < 4; ++r) {                        \
          int qg = q0w + lhi * 4 + r;                                          \
          if (kg > qg) sacc[s][r] = -3.0e38f;                                  \
        }                                                                      \
      }                                                                        \
    }                                                                          \
    float corr[4];                                                             \
    bool nr[4];                                                                \
    _Pragma("unroll") for (int r = 0; r < 4; ++r) {                            \
      float mx = fmaxf(fmaxf(sacc[0][r], sacc[1][r]),                          \
                       fmaxf(sacc[2][r], sacc[3][r]));                         \
      _Pragma("unroll") for (int off = 1; off <= 8; off <<= 1)                 \
          mx = fmaxf(mx, __shfl_xor(mx, off));                                 \
      nr[r] = !__all(mx <= m_[r] + 8.0f);                                      \
      if (nr[r]) {                                                             \
        float mnew = fmaxf(m_[r], mx);                                         \
        corr[r] = exp2f(m_[r] - mnew);                                         \
        m_[r] = mnew;                                                          \
        l_[r] *= corr[r];                                                      \
      }                                                                        \
      float ps = 0.f;                                                          \
      _Pragma("unroll") for (int s = 0; s < 4; ++s) {                          \
        float p = exp2f(sacc[s][r] - m_[r]);                                   \
        ps += p;                                                               \
        PW[lhi * 4 + r][s * 16 + lrow] = f2bf_fast(p);                         \
      }                                                                        \
      _Pragma("unroll") for (int off = 1; off <= 8; off <<= 1)                 \
          ps += __shfl_xor(ps, off);                                           \
      l_[r] += ps;                                                             \
    }                                                                          \
    _Pragma("unroll") for (int r = 0; r < 4; ++r)                              \
      if (nr[r]) {                                                             \
        _Pragma("unroll") for (int ds = 0; ds < 4; ++ds) o[ds][r] *= corr[r];  \
      }                                                                        \
    _Pragma("unroll") for (int ks = 0; ks < 2; ++ks) {                         \
      bf16x8 pa = *(const bf16x8*)&PW[lrow][ks * 32 + lhi * 8];                \
      _Pragma("unroll") for (int ds = 0; ds < 4; ++ds)                         \
        o[ds] = __builtin_amdgcn_mfma_f32_16x16x32_bf16(                       \
            pa, vf[ks * 4 + ds], o[ds], 0, 0, 0);                              \
    }                                                                          \
    kb += 64;                                                                  \
  }

  while (true) {
    ATTN_STEP(kA, kB)
    if (kb >= kend) break;
    ATTN_STEP(kB, kA)
    if (kb >= kend) break;
  }
#undef ATTN_STEP

  // epilogue
#pragma unroll
  for (int r = 0; r < 4; ++r) {
    float inv = 1.0f / l_[r];
    int q = q0w + lhi * 4 + r;
#pragma unroll
    for (int ds = 0; ds < 4; ++ds)
      Y[((size_t)(b * TSEQ + q)) * N_EMBD + h * HS + ds * 16 + lrow] =
          f2bf(o[ds][r] * inv);
  }
}

extern "C" void kernel_launch(void* const* d_in, const int* in_sizes, int n_in,
                              void* d_out, int out_size, void* d_ws, size_t ws_size,
                              hipStream_t stream) {
  const float* x      = (const float*)d_in[0];
  const float* W_attn = (const float*)d_in[1];
  const float* b_attn = (const float*)d_in[2];
  const float* W_proj = (const float*)d_in[3];
  const float* b_proj = (const float*)d_in[4];
  float* out = (float*)d_out;

  u16* xb  = (u16*)d_ws;
  u16* Wat = xb  + (size_t)BT * N_EMBD;
  u16* Wpt = Wat + (size_t)3 * N_EMBD * N_EMBD;
  u16* Qb  = Wpt + (size_t)N_EMBD * N_EMBD;
  u16* Kb  = Qb  + (size_t)BT * N_EMBD;
  u16* Vt  = Kb  + (size_t)BT * N_EMBD;
  u16* yb  = Vt  + (size_t)BT * N_EMBD;

  cvt_bf16<<<(BT * N_EMBD / 4 + 255) / 256, 256, 0, stream>>>(x, xb, BT * N_EMBD / 4);
  {
    dim3 g1(3 * N_EMBD / 32, N_EMBD / 32);
    transpose_cvt<<<g1, 256, 0, stream>>>(W_attn, Wat, N_EMBD, 3 * N_EMBD);
    dim3 g2(N_EMBD / 32, N_EMBD / 32);
    transpose_cvt<<<g2, 256, 0, stream>>>(W_proj, Wpt, N_EMBD, N_EMBD);
  }
  {
    dim3 grid(3 * N_EMBD / 128, BT / 128);
    gemm_qkv_bf16<<<grid, 256, 0, stream>>>(xb, Wat, b_attn, Qb, Kb, Vt);
  }
  {
    attn_mfma<<<1024, 256, 0, stream>>>(Qb, Kb, Vt, yb);
  }
  {
    dim3 grid(N_EMBD / 128, BT / 128);
    gemm_proj_bf16<<<grid, 256, 0, stream>>>(yb, Wpt, b_proj, out);
  }
}

// Round 8
// 210.505 us; speedup vs baseline: 1.5115x; 1.3115x over previous
//
#include <hip/hip_runtime.h>
#include <hip/hip_bf16.h>
#include <math.h>

#define N_EMBD 1024
#define N_HEAD 16
#define HS 64
#define BT 4096
#define TSEQ 2048

typedef float f32x4 __attribute__((ext_vector_type(4)));
typedef short bf16x8 __attribute__((ext_vector_type(8)));
typedef unsigned short u16;

static __device__ __forceinline__ u16 f2bf(float f) {
  union { float f; unsigned int u; } c; c.f = f;
  unsigned int r = c.u + 0x7FFFu + ((c.u >> 16) & 1u);   // RNE
  return (u16)(r >> 16);
}

static __device__ __forceinline__ u16 f2bf_fast(float f) {
  union { __hip_bfloat16 h; u16 u; } cv;
  cv.h = __float2bfloat16(f);
  return cv.u;
}

// ---------------- prep: fp32 -> bf16 elementwise (x)
__global__ __launch_bounds__(256) void cvt_bf16(const float* __restrict__ in,
                                                u16* __restrict__ out, int n4) {
  int i = blockIdx.x * 256 + threadIdx.x;
  if (i < n4) {
    float4 v = ((const float4*)in)[i];
    ushort4 o;
    o.x = f2bf(v.x); o.y = f2bf(v.y); o.z = f2bf(v.z); o.w = f2bf(v.w);
    ((ushort4*)out)[i] = o;
  }
}

// ---------------- prep: W[K][N] fp32 -> Wt[N][K] bf16 (32x32 LDS transpose)
__global__ __launch_bounds__(256) void transpose_cvt(const float* __restrict__ W,
                                                     u16* __restrict__ Wt,
                                                     int K, int N) {
  __shared__ u16 Ls[32][36];
  const int n0 = blockIdx.x * 32, k0 = blockIdx.y * 32;
  const int t = threadIdx.x;
  {
    int kk = t >> 3, nn4 = (t & 7) * 4;
    float4 v = *(const float4*)(W + (size_t)(k0 + kk) * N + n0 + nn4);
    Ls[kk][nn4 + 0] = f2bf(v.x); Ls[kk][nn4 + 1] = f2bf(v.y);
    Ls[kk][nn4 + 2] = f2bf(v.z); Ls[kk][nn4 + 3] = f2bf(v.w);
  }
  __syncthreads();
  {
    int nn = t >> 3, kk4 = (t & 7) * 4;
    ushort4 o;
    o.x = Ls[kk4 + 0][nn]; o.y = Ls[kk4 + 1][nn];
    o.z = Ls[kk4 + 2][nn]; o.w = Ls[kk4 + 3][nn];
    *(ushort4*)(Wt + (size_t)(n0 + nn) * K + k0 + kk4) = o;
  }
}

// ---------------- bf16 MFMA GEMM core (m97 structure)
#define BKS 32

__device__ __forceinline__ int swz(int row, int c) {
  return row * 4 + (c ^ ((row >> 1) & 3));
}

__device__ __forceinline__ void stage128x32(const u16* __restrict__ G, int ldk,
                                            u16* lds, int w, int lane) {
#pragma unroll
  for (int i = 0; i < 2; ++i) {
    int s = i * 256 + w * 64 + lane;
    int row = s >> 2, c = s & 3;
    int csrc = c ^ ((row >> 1) & 3);
    const u16* src = G + (size_t)row * ldk + csrc * 8;
    u16* dst = lds + (size_t)(i * 256 + w * 64) * 8;
    __builtin_amdgcn_global_load_lds(
        (const __attribute__((address_space(1))) void*)src,
        (__attribute__((address_space(3))) void*)dst, 16, 0, 0);
  }
}

#define GEMM_MAIN_LOOP(Aptr, Bptr, Kdim)                                        \
  __shared__ u16 sm[2][2][128 * BKS];                                           \
  const int tid = threadIdx.x, lane = tid & 63, w = tid >> 6;                   \
  const int wr = w >> 1, wc = w & 1, lrow = lane & 15, lhi = lane >> 4;         \
  const int bm = blockIdx.y * 128, bn = blockIdx.x * 128;                       \
  f32x4 acc[4][4];                                                              \
  _Pragma("unroll") for (int i = 0; i < 4; ++i)                                 \
      _Pragma("unroll") for (int j = 0; j < 4; ++j)                             \
          acc[i][j] = (f32x4){0.f, 0.f, 0.f, 0.f};                              \
  stage128x32(Aptr + (size_t)bm * Kdim, Kdim, sm[0][0], w, lane);               \
  stage128x32(Bptr + (size_t)bn * Kdim, Kdim, sm[0][1], w, lane);               \
  __syncthreads();                                                              \
  const int NT = Kdim / BKS;                                                    \
  for (int t = 0; t < NT; ++t) {                                                \
    int cur = t & 1, nxt = cur ^ 1;                                             \
    if (t + 1 < NT) {                                                           \
      stage128x32(Aptr + (size_t)bm * Kdim + (t + 1) * BKS, Kdim, sm[nxt][0],   \
                  w, lane);                                                     \
      stage128x32(Bptr + (size_t)bn * Kdim + (t + 1) * BKS, Kdim, sm[nxt][1],   \
                  w, lane);                                                     \
    }                                                                           \
    const u16* As = sm[cur][0];                                                 \
    const u16* Bs = sm[cur][1];                                                 \
    bf16x8 af[4], bfr[4];                                                       \
    _Pragma("unroll") for (int mi = 0; mi < 4; ++mi) {                          \
      int row = wr * 64 + mi * 16 + lrow;                                       \
      af[mi] = *(const bf16x8*)(As + (size_t)swz(row, lhi) * 8);                \
    }                                                                           \
    _Pragma("unroll") for (int nj = 0; nj < 4; ++nj) {                          \
      int row = wc * 64 + nj * 16 + lrow;                                       \
      bfr[nj] = *(const bf16x8*)(Bs + (size_t)swz(row, lhi) * 8);               \
    }                                                                           \
    _Pragma("unroll") for (int mi = 0; mi < 4; ++mi)                            \
        _Pragma("unroll") for (int nj = 0; nj < 4; ++nj)                        \
            acc[mi][nj] = __builtin_amdgcn_mfma_f32_16x16x32_bf16(              \
                af[mi], bfr[nj], acc[mi][nj], 0, 0, 0);                         \
    __syncthreads();                                                            \
  }

// QKV GEMM epilogue -> Qb (scaled by 0.125*log2e), Kb, Vt
__global__ __launch_bounds__(256) void gemm_qkv_bf16(
    const u16* __restrict__ Ab, const u16* __restrict__ Btr,
    const float* __restrict__ bias,
    u16* __restrict__ Qb, u16* __restrict__ Kb, u16* __restrict__ Vt) {
  GEMM_MAIN_LOOP(Ab, Btr, N_EMBD)
  const int sector = bn >> 10;
  const float QSC = 0.125f * 1.44269504f;   // fold log2(e) for exp2 softmax
#pragma unroll
  for (int nj = 0; nj < 4; ++nj) {
    int n = bn + wc * 64 + nj * 16 + lrow;
    int h = (n & 1023) >> 6, d = n & 63;
    float bv = bias[n];
#pragma unroll
    for (int mi = 0; mi < 4; ++mi) {
      int mbase = bm + wr * 64 + mi * 16 + lhi * 4;
      int bb_ = mbase >> 11, tt = mbase & 2047;
      if (sector == 0) {
#pragma unroll
        for (int r = 0; r < 4; ++r)
          Qb[((size_t)(bb_ * 16 + h) * TSEQ + tt + r) * HS + d] =
              f2bf((acc[mi][nj][r] + bv) * QSC);
      } else if (sector == 1) {
#pragma unroll
        for (int r = 0; r < 4; ++r)
          Kb[((size_t)(bb_ * 16 + h) * TSEQ + tt + r) * HS + d] =
              f2bf(acc[mi][nj][r] + bv);
      } else {
        ushort4 o;
        o.x = f2bf(acc[mi][nj][0] + bv); o.y = f2bf(acc[mi][nj][1] + bv);
        o.z = f2bf(acc[mi][nj][2] + bv); o.w = f2bf(acc[mi][nj][3] + bv);
        *(ushort4*)(Vt + ((size_t)(bb_ * 16 + h) * HS + d) * TSEQ + tt) = o;
      }
    }
  }
}

// Proj GEMM epilogue -> fp32 out + bias
__global__ __launch_bounds__(256) void gemm_proj_bf16(
    const u16* __restrict__ Ab, const u16* __restrict__ Btr,
    const float* __restrict__ bias, float* __restrict__ C) {
  GEMM_MAIN_LOOP(Ab, Btr, N_EMBD)
#pragma unroll
  for (int nj = 0; nj < 4; ++nj) {
    int n = bn + wc * 64 + nj * 16 + lrow;
    float bv = bias[n];
#pragma unroll
    for (int mi = 0; mi < 4; ++mi) {
      int mbase = bm + wr * 64 + mi * 16 + lhi * 4;
#pragma unroll
      for (int r = 0; r < 4; ++r)
        C[(size_t)(mbase + r) * N_EMBD + n] = acc[mi][nj][r] + bv;
    }
  }
}

// ---------------- MFMA flash attention v5
// ONE wave per block, one 16-row q-tile per wave; 4096 blocks (= all tiles).
// R5's proven 112-VGPR body (no spill), launch_bounds(64,2) (cap 256, HW fits
// 4 waves/SIMD at 112). Long tiles dispatch first; each XCD walks 4 bh
// sequentially -> ~1MB live K/V per XCD L2. K reg-dbuf; V issue-early;
// defer-rescale THR=8 (log2 domain).
struct Kfrag { bf16x8 r[8]; };

__device__ __forceinline__ void loadK(const u16* __restrict__ Kh, int kb,
                                      int lrow, int lhi, Kfrag& kf) {
#pragma unroll
  for (int s = 0; s < 4; ++s) {
    const u16* base = Kh + (size_t)(kb + 16 * s + lrow) * HS + lhi * 8;
    kf.r[2 * s]     = *(const bf16x8*)(base);
    kf.r[2 * s + 1] = *(const bf16x8*)(base + 32);
  }
}

__global__ __launch_bounds__(64, 2) void attn_mfma(
    const u16* __restrict__ Qb, const u16* __restrict__ Kb,
    const u16* __restrict__ Vt, u16* __restrict__ Y) {
  __shared__ u16 Plds[16][72];

  const int lane = threadIdx.x;
  const int lrow = lane & 15;
  const int lhi  = lane >> 4;

  const int wg  = blockIdx.x;                  // 0..4095
  const int xcd = wg & 7;
  const int lin = wg >> 3;                     // 0..511
  const int bh  = (xcd << 2) | (lin >> 7);     // 4 bh per XCD, walked serially
  const int itile = 127 - (lin & 127);         // long tiles first
  const int b   = bh >> 4, h = bh & 15;

  const u16* Qh = Qb + (size_t)bh * TSEQ * HS;
  const u16* Kh = Kb + (size_t)bh * TSEQ * HS;
  const u16* Vh = Vt + (size_t)bh * HS * TSEQ;

  const int q0w  = itile * 16;
  const int kend = ((itile >> 2) + 1) * 64;    // keys rounded up to 64

  bf16x8 aq0 = *(const bf16x8*)(Qh + (size_t)(q0w + lrow) * HS + lhi * 8);
  bf16x8 aq1 = *(const bf16x8*)(Qh + (size_t)(q0w + lrow) * HS + 32 + lhi * 8);

  f32x4 o[4];
  float m_[4], l_[4];
#pragma unroll
  for (int r = 0; r < 4; ++r) { m_[r] = -INFINITY; l_[r] = 0.f; }
#pragma unroll
  for (int ds = 0; ds < 4; ++ds) o[ds] = (f32x4){0.f, 0.f, 0.f, 0.f};

  Kfrag kA, kB;
  loadK(Kh, 0, lrow, lhi, kA);
  int kb = 0;

#define ATTN_STEP(KC, KN)                                                      \
  {                                                                            \
    bf16x8 vf[8];                                                              \
    _Pragma("unroll") for (int ks = 0; ks < 2; ++ks)                           \
      _Pragma("unroll") for (int ds = 0; ds < 4; ++ds)                         \
        vf[ks * 4 + ds] = *(const bf16x8*)(                                    \
            Vh + (size_t)(ds * 16 + lrow) * TSEQ + kb + ks * 32 + lhi * 8);    \
    if (kb + 64 < kend) loadK(Kh, kb + 64, lrow, lhi, KN);                     \
    f32x4 sacc[4];                                                             \
    _Pragma("unroll") for (int s = 0; s < 4; ++s) {                            \
      f32x4 z = (f32x4){0.f, 0.f, 0.f, 0.f};                                   \
      z = __builtin_amdgcn_mfma_f32_16x16x32_bf16(aq0, KC.r[2 * s], z, 0, 0, 0); \
      z = __builtin_amdgcn_mfma_f32_16x16x32_bf16(aq1, KC.r[2 * s + 1], z, 0, 0, 0); \
      sacc[s] = z;                                                             \
    }                                                                          \
    const bool last = (kb + 64 >= kend);                                       \
    if (last) {                                                                \
      _Pragma("unroll") for (int s = 0; s < 4; ++s) {                          \
        int kg = kb + 16 * s + lrow;                                           \
        _Pragma("unroll") for (int r = 0; r < 4; ++r) {                        \
          int qg = q0w + lhi * 4 + r;                                          \
          if (kg > qg) sacc[s][r] = -3.0e38f;                                  \
        }                                                                      \
      }                                                                        \
    }                                                                          \
    float corr[4];                                                             \
    bool nr[4];                                                                \
    _Pragma("unroll") for (int r = 0; r < 4; ++r) {                            \
      float mx = fmaxf(fmaxf(sacc[0][r], sacc[1][r]),                          \
                       fmaxf(sacc[2][r], sacc[3][r]));                         \
      _Pragma("unroll") for (int off = 1; off <= 8; off <<= 1)                 \
          mx = fmaxf(mx, __shfl_xor(mx, off));                                 \
      nr[r] = !__all(mx <= m_[r] + 8.0f);                                      \
      if (nr[r]) {                                                             \
        float mnew = fmaxf(m_[r], mx);                                         \
        corr[r] = exp2f(m_[r] - mnew);                                         \
        m_[r] = mnew;                                                          \
        l_[r] *= corr[r];                                                      \
      }                                                                        \
      float ps = 0.f;                                                          \
      _Pragma("unroll") for (int s = 0; s < 4; ++s) {                          \
        float p = exp2f(sacc[s][r] - m_[r]);                                   \
        ps += p;                                                               \
        Plds[lhi * 4 + r][s * 16 + lrow] = f2bf_fast(p);                       \
      }                                                                        \
      _Pragma("unroll") for (int off = 1; off <= 8; off <<= 1)                 \
          ps += __shfl_xor(ps, off);                                           \
      l_[r] += ps;                                                             \
    }                                                                          \
    _Pragma("unroll") for (int r = 0; r < 4; ++r)                              \
      if (nr[r]) {                                                             \
        _Pragma("unroll") for (int ds = 0; ds < 4; ++ds) o[ds][r] *= corr[r];  \
      }                                                                        \
    _Pragma("unroll") for (int ks = 0; ks < 2; ++ks) {                         \
      bf16x8 pa = *(const bf16x8*)&Plds[lrow][ks * 32 + lhi * 8];              \
      _Pragma("unroll") for (int ds = 0; ds < 4; ++ds)                         \
        o[ds] = __builtin_amdgcn_mfma_f32_16x16x32_bf16(                       \
            pa, vf[ks * 4 + ds], o[ds], 0, 0, 0);                              \
    }                                                                          \
    kb += 64;                                                                  \
  }

  while (true) {
    ATTN_STEP(kA, kB)
    if (kb >= kend) break;
    ATTN_STEP(kB, kA)
    if (kb >= kend) break;
  }
#undef ATTN_STEP

  // epilogue
#pragma unroll
  for (int r = 0; r < 4; ++r) {
    float inv = 1.0f / l_[r];
    int q = q0w + lhi * 4 + r;
#pragma unroll
    for (int ds = 0; ds < 4; ++ds)
      Y[((size_t)(b * TSEQ + q)) * N_EMBD + h * HS + ds * 16 + lrow] =
          f2bf(o[ds][r] * inv);
  }
}

extern "C" void kernel_launch(void* const* d_in, const int* in_sizes, int n_in,
                              void* d_out, int out_size, void* d_ws, size_t ws_size,
                              hipStream_t stream) {
  const float* x      = (const float*)d_in[0];
  const float* W_attn = (const float*)d_in[1];
  const float* b_attn = (const float*)d_in[2];
  const float* W_proj = (const float*)d_in[3];
  const float* b_proj = (const float*)d_in[4];
  float* out = (float*)d_out;

  u16* xb  = (u16*)d_ws;
  u16* Wat = xb  + (size_t)BT * N_EMBD;
  u16* Wpt = Wat + (size_t)3 * N_EMBD * N_EMBD;
  u16* Qb  = Wpt + (size_t)N_EMBD * N_EMBD;
  u16* Kb  = Qb  + (size_t)BT * N_EMBD;
  u16* Vt  = Kb  + (size_t)BT * N_EMBD;
  u16* yb  = Vt  + (size_t)BT * N_EMBD;

  cvt_bf16<<<(BT * N_EMBD / 4 + 255) / 256, 256, 0, stream>>>(x, xb, BT * N_EMBD / 4);
  {
    dim3 g1(3 * N_EMBD / 32, N_EMBD / 32);
    transpose_cvt<<<g1, 256, 0, stream>>>(W_attn, Wat, N_EMBD, 3 * N_EMBD);
    dim3 g2(N_EMBD / 32, N_EMBD / 32);
    transpose_cvt<<<g2, 256, 0, stream>>>(W_proj, Wpt, N_EMBD, N_EMBD);
  }
  {
    dim3 grid(3 * N_EMBD / 128, BT / 128);
    gemm_qkv_bf16<<<grid, 256, 0, stream>>>(xb, Wat, b_attn, Qb, Kb, Vt);
  }
  {
    attn_mfma<<<4096, 64, 0, stream>>>(Qb, Kb, Vt, yb);
  }
  {
    dim3 grid(N_EMBD / 128, BT / 128);
    gemm_proj_bf16<<<grid, 256, 0, stream>>>(yb, Wpt, b_proj, out);
  }
}